// Round 1
// baseline (126.708 us; speedup 1.0000x reference)
//
#include <hip/hip_runtime.h>

#define BATCH 16
#define NN 1024
#define FF 128

typedef __attribute__((ext_vector_type(8))) short bf16x8;
typedef __attribute__((ext_vector_type(4))) float f32x4;

__device__ __forceinline__ unsigned short f2bf(float x) {
  unsigned u = __float_as_uint(x);
  u += 0x7fff + ((u >> 16) & 1);   // round-to-nearest-even
  return (unsigned short)(u >> 16);
}
__device__ __forceinline__ float bf2f(unsigned short b) {
  return __uint_as_float(((unsigned)b) << 16);
}

// ---------------------------------------------------------------------------
// K1: deg[b,n] = 1 + sum_m A[b,n,m];  d = rsqrt(deg).  One wave per row.
// ---------------------------------------------------------------------------
__global__ __launch_bounds__(256) void k_deg(const float* __restrict__ A,
                                             float* __restrict__ d) {
  int row  = blockIdx.x * 4 + (threadIdx.x >> 6);
  int lane = threadIdx.x & 63;
  const float4* Ar = (const float4*)(A + (size_t)row * NN);
  float s = 0.f;
#pragma unroll
  for (int i = 0; i < 4; ++i) {
    float4 v = Ar[lane + i * 64];
    s += (v.x + v.y) + (v.z + v.w);
  }
#pragma unroll
  for (int off = 32; off > 0; off >>= 1) s += __shfl_down(s, off, 64);
  if (lane == 0) d[row] = rsqrtf(s + 1.0f);
}

// ---------------------------------------------------------------------------
// K0: Wt[g][f] = bf16(W[f][g])  (128x128, trivial)
// ---------------------------------------------------------------------------
__global__ __launch_bounds__(256) void k_wt(const float* __restrict__ W,
                                            unsigned short* __restrict__ Wt) {
  int id = blockIdx.x * 256 + threadIdx.x;
  int g = id >> 7, f = id & 127;
  Wt[g * 128 + f] = f2bf(W[f * 128 + g]);
}

// ---------------------------------------------------------------------------
// K2: Yt[b][g][m] = bf16( d[b,m] * sum_f X[b,m,f] * W[f,g] )
// MFMA GEMM: M=16384 (m), N=128 (g), K=128. BM=64, grid=256 WGs.
// ---------------------------------------------------------------------------
#define K2S 152  // LDS row stride (elements): 304B = 16B-aligned, bank-step 12 -> 2-way (free)
__global__ __launch_bounds__(256) void k_xw(const float* __restrict__ X,
                                            const unsigned short* __restrict__ Wt,
                                            const float* __restrict__ d,
                                            unsigned short* __restrict__ Yt) {
  __shared__ __align__(16) unsigned short Xl[64 * K2S];
  __shared__ __align__(16) unsigned short Wl[128 * K2S];
  __shared__ float dl[64];
  int b  = blockIdx.x >> 4;
  int m0 = (blockIdx.x & 15) * 64;
  int t  = threadIdx.x;

  // stage X tile (64x128 fp32 -> bf16)
#pragma unroll
  for (int i = 0; i < 8; ++i) {
    int s = t + i * 256;
    int r = s >> 5, f4 = (s & 31) * 4;
    float4 v = *(const float4*)(X + ((size_t)(b * NN + m0 + r) * FF + f4));
    ushort4 p; p.x = f2bf(v.x); p.y = f2bf(v.y); p.z = f2bf(v.z); p.w = f2bf(v.w);
    *(ushort4*)(&Xl[r * K2S + f4]) = p;
  }
  // stage Wt (already bf16, 128x128)
#pragma unroll
  for (int i = 0; i < 8; ++i) {
    int s = t + i * 256;
    int g = s >> 4, c8 = (s & 15) * 8;
    uint4 v = *(const uint4*)(Wt + (g * 128 + c8));
    *(uint4*)(&Wl[g * K2S + c8]) = v;
  }
  if (t < 64) dl[t] = d[b * NN + m0 + t];
  __syncthreads();

  int wave = t >> 6, lane = t & 63;
  int wr = wave >> 1, wc = wave & 1;
  int quad = lane >> 4, l16 = lane & 15;

  f32x4 acc[2][4];
#pragma unroll
  for (int mt = 0; mt < 2; ++mt)
#pragma unroll
    for (int ct = 0; ct < 4; ++ct) acc[mt][ct] = (f32x4){0.f, 0.f, 0.f, 0.f};

#pragma unroll
  for (int k0 = 0; k0 < 128; k0 += 32) {
    bf16x8 a[2], bb[4];
#pragma unroll
    for (int mt = 0; mt < 2; ++mt) {
      int m = wr * 32 + mt * 16 + l16;
      a[mt] = *(const bf16x8*)(&Xl[m * K2S + k0 + quad * 8]);
    }
#pragma unroll
    for (int ct = 0; ct < 4; ++ct) {
      int g = wc * 64 + ct * 16 + l16;
      bb[ct] = *(const bf16x8*)(&Wl[g * K2S + k0 + quad * 8]);
    }
#pragma unroll
    for (int mt = 0; mt < 2; ++mt)
#pragma unroll
      for (int ct = 0; ct < 4; ++ct)
        acc[mt][ct] = __builtin_amdgcn_mfma_f32_16x16x32_bf16(a[mt], bb[ct], acc[mt][ct], 0, 0, 0);
  }

  // epilogue: scale by d[m], store transposed Yt[b][g][m] (4 consecutive m per lane)
#pragma unroll
  for (int mt = 0; mt < 2; ++mt) {
    int mb = wr * 32 + mt * 16 + quad * 4;  // local m base (C/D rows = quad*4+reg)
#pragma unroll
    for (int ct = 0; ct < 4; ++ct) {
      int g = wc * 64 + ct * 16 + l16;      // C/D col = lane&15
      ushort4 p;
      p.x = f2bf(dl[mb + 0] * acc[mt][ct][0]);
      p.y = f2bf(dl[mb + 1] * acc[mt][ct][1]);
      p.z = f2bf(dl[mb + 2] * acc[mt][ct][2]);
      p.w = f2bf(dl[mb + 3] * acc[mt][ct][3]);
      *(ushort4*)(Yt + ((size_t)(b * 128 + g) * NN + m0 + mb)) = p;
    }
  }
}

// ---------------------------------------------------------------------------
// K3: out[b,n,g] = d[n] * ( sum_m A[b,n,m]*Yt[b,g,m]  + Yt[b,g,n] )
// Per-batch GEMM 1024x128x1024. BM=32, BN=128, BK=32; grid = 16*32 = 512 WGs.
// A converted fp32->bf16 during staging; register prefetch of next K-tile.
// ---------------------------------------------------------------------------
#define K3S 56   // LDS row stride (elements): 112B = 16B-aligned, bank-step 28 -> 2-way (free)
__global__ __launch_bounds__(256) void k_agg(const float* __restrict__ A,
                                             const unsigned short* __restrict__ Yt,
                                             const float* __restrict__ d,
                                             float* __restrict__ out) {
  __shared__ __align__(16) unsigned short Al[32 * K3S];
  __shared__ __align__(16) unsigned short Yl[128 * K3S];
  int b  = blockIdx.x >> 5;
  int n0 = (blockIdx.x & 31) * 32;
  int t  = threadIdx.x;
  int wave = t >> 6, lane = t & 63;
  int wr = wave >> 1, wc = wave & 1;
  int quad = lane >> 4, l16 = lane & 15;

  // A staging: 256 slots = 32 rows x 8 float4
  int ar = t >> 3, ac4 = (t & 7) * 4;
  const float* Ap = A + ((size_t)(b * NN + n0 + ar) * NN + ac4);
  // Y staging: 512 slots = 128 g-rows x 4 x (8 bf16); thread handles slots t, t+256
  int yg0 = t >> 2,         yc0 = (t & 3) * 8;
  int yg1 = (t + 256) >> 2, yc1 = ((t + 256) & 3) * 8;
  const unsigned short* Yp0 = Yt + ((size_t)(b * 128 + yg0) * NN + yc0);
  const unsigned short* Yp1 = Yt + ((size_t)(b * 128 + yg1) * NN + yc1);

  f32x4 acc[4];
#pragma unroll
  for (int ct = 0; ct < 4; ++ct) acc[ct] = (f32x4){0.f, 0.f, 0.f, 0.f};

  // prefetch k-tile 0
  float4 av = *(const float4*)(Ap);
  uint4 yv0 = *(const uint4*)(Yp0);
  uint4 yv1 = *(const uint4*)(Yp1);

  for (int k0 = 0; k0 < NN; k0 += 32) {
    __syncthreads();  // previous tile's LDS reads complete
    ushort4 ap; ap.x = f2bf(av.x); ap.y = f2bf(av.y); ap.z = f2bf(av.z); ap.w = f2bf(av.w);
    *(ushort4*)(&Al[ar * K3S + ac4]) = ap;
    *(uint4*)(&Yl[yg0 * K3S + yc0]) = yv0;
    *(uint4*)(&Yl[yg1 * K3S + yc1]) = yv1;
    __syncthreads();  // staged data visible

    if (k0 + 32 < NN) {   // prefetch next tile (overlaps with MFMA below)
      av  = *(const float4*)(Ap  + k0 + 32);
      yv0 = *(const uint4*)(Yp0 + k0 + 32);
      yv1 = *(const uint4*)(Yp1 + k0 + 32);
    }

    bf16x8 af = *(const bf16x8*)(&Al[(wr * 16 + l16) * K3S + quad * 8]);
#pragma unroll
    for (int ct = 0; ct < 4; ++ct) {
      bf16x8 bf = *(const bf16x8*)(&Yl[(wc * 64 + ct * 16 + l16) * K3S + quad * 8]);
      acc[ct] = __builtin_amdgcn_mfma_f32_16x16x32_bf16(af, bf, acc[ct], 0, 0, 0);
    }
  }

  // epilogue: out[n,g] = d[n] * (acc + Y[n,g]);  C/D: row=quad*4+reg, col=lane&15
  int nb = n0 + wr * 16 + quad * 4;
  float4 d4 = *(const float4*)(d + b * NN + nb);
#pragma unroll
  for (int ct = 0; ct < 4; ++ct) {
    int g = wc * 64 + ct * 16 + l16;
    ushort4 yv = *(const ushort4*)(Yt + ((size_t)(b * 128 + g) * NN + nb));
    float* op = out + ((size_t)(b * NN + nb) * FF + g);
    op[0 * FF] = d4.x * (acc[ct][0] + bf2f(yv.x));
    op[1 * FF] = d4.y * (acc[ct][1] + bf2f(yv.y));
    op[2 * FF] = d4.z * (acc[ct][2] + bf2f(yv.z));
    op[3 * FF] = d4.w * (acc[ct][3] + bf2f(yv.w));
  }
}

// ---------------------------------------------------------------------------
extern "C" void kernel_launch(void* const* d_in, const int* in_sizes, int n_in,
                              void* d_out, int out_size, void* d_ws, size_t ws_size,
                              hipStream_t stream) {
  const float* X = (const float*)d_in[0];  // [16,1024,128]
  const float* A = (const float*)d_in[1];  // [16,1024,1024]
  const float* W = (const float*)d_in[2];  // [128,128]
  float* out = (float*)d_out;              // [16,1024,128]

  char* ws = (char*)d_ws;
  float*          dinv = (float*)ws;                              // 64 KB
  unsigned short* Wt   = (unsigned short*)(ws + 65536);           // 32 KB
  unsigned short* Yt   = (unsigned short*)(ws + 65536 + 32768);   // 4 MB  [b][g][m]

  k_deg<<<dim3(4096), dim3(256), 0, stream>>>(A, dinv);
  k_wt <<<dim3(64),   dim3(256), 0, stream>>>(W, Wt);
  k_xw <<<dim3(256),  dim3(256), 0, stream>>>(X, Wt, dinv, Yt);
  k_agg<<<dim3(512),  dim3(256), 0, stream>>>(A, Yt, dinv, out);
}